// Round 7
// baseline (215.165 us; speedup 1.0000x reference)
//
#include <hip/hip_runtime.h>

// RelationalGraphConvLayer: out[b,m,u] = relu(sum_e (adj[b,e]@feat[b]) @ ker[b,e])
// B=256, E=5, N=128, ATOM=64, UNITS=128, fp32 in/out, bf16 MFMA compute.
//
// v7: two-kernel split with fine-grained backfill (v0-v6 all pinned at ~60 us
// regardless of structure; common denominator was grid=256 = exactly one block
// per CU, zero backfill -> dispatch = max over 256 block times).
//   A (1280 blocks): W[b,e] = bf16(feat[b] @ ker[b,e]) -> workspace, stored in
//     MFMA B-frag layout (coalesced 8B stores).
//   B (2048 blocks, 16-row octants): out = relu(sum_e adj[e] @ W[e]).
//     NO LDS, NO barriers: adj reg-direct A-frags, W-frags coalesced 16B global
//     loads (L2/L3-hot). W[e] issued before adj[e+1] -> counted vmcnt waits.
// Falls back to the verified v6 single kernel if ws_size is insufficient.

typedef __attribute__((ext_vector_type(8))) short s8v;  // 8 x bf16 MFMA A/B frag
typedef __attribute__((ext_vector_type(4))) short s4v;  // 4 x bf16 packed store
typedef __attribute__((ext_vector_type(4))) float f4v;  // MFMA C/D frag / float4

__device__ __forceinline__ short f2bf(float f) {
    // fp32 -> bf16 round-to-nearest-even (inputs finite; no NaN handling needed)
    unsigned u = __builtin_bit_cast(unsigned, f);
    u += 0x7FFFu + ((u >> 16) & 1u);
    return (short)(u >> 16);
}

__device__ __forceinline__ void lds_barrier() {
    asm volatile("s_waitcnt lgkmcnt(0)" ::: "memory");
    __builtin_amdgcn_s_barrier();
    __builtin_amdgcn_sched_barrier(0);
}

// ---------------------------------------------------------------------------
// Kernel A: W[b,e] = feat[b] @ ker[b,e]  (128n x 128u, K=64), bf16 out in
// B-frag layout: tile (u16*4 + k32), lane l, j:  W[32*k32+8*(l>>4)+j][16*u16+(l&15)]
// ---------------------------------------------------------------------------
__global__ __launch_bounds__(256, 4)
void w_kernel(const float* __restrict__ feat,
              const float* __restrict__ ker,
              short* __restrict__ wsF)
{
    __shared__ __align__(16) short kerF[16 * 512];  // 16 KB, tiles (u16*2+kk)

    const int bid  = blockIdx.x;          // = b*5 + e
    const int b    = bid / 5;
    const int tid  = threadIdx.x;
    const int w    = tid >> 6;            // wave 0..3 -> u16 pair {2w, 2w+1}
    const int lane = tid & 63;
    const int c16  = lane & 15;
    const int qd   = lane >> 4;

    const float* keG  = ker  + (size_t)bid * (64 * 128);
    const float* feB  = feat + (size_t)b * (128 * 64);
    short*       wOut = wsF  + (size_t)bid * 16384;

    // ---- stage ker[b,e] into frag-order LDS (coalesced-ish f4v row loads,
    //      scalar b16 scatter -- only 16 KB, one-time) ----
    {
        const int d  = tid >> 2;          // 0..63
        const int u0 = (tid & 3) * 32;
        const float* kp = keG + d * 128 + u0;
        f4v kv[8];
        #pragma unroll
        for (int i = 0; i < 8; ++i) kv[i] = *(const f4v*)(kp + 4 * i);
        const int kk = d >> 5, q = (d >> 3) & 3, j = d & 7;
        #pragma unroll
        for (int i = 0; i < 8; ++i)
            #pragma unroll
            for (int c = 0; c < 4; ++c) {
                const int u = u0 + 4 * i + c;
                kerF[((u >> 4) * 2 + kk) * 512 + (q * 16 + (u & 15)) * 8 + j] = f2bf(kv[i][c]);
            }
    }
    __syncthreads();

    // ---- compute + store W frags ----
    #pragma unroll
    for (int n16 = 0; n16 < 8; ++n16) {
        // feat A-frags direct from global: lane l reads feat[16n16+c16][8qd+j (+32 for kk=1)]
        const float* fp = feB + (16 * n16 + c16) * 64 + 8 * qd;
        f4v f00 = *(const f4v*)(fp);
        f4v f01 = *(const f4v*)(fp + 4);
        f4v f10 = *(const f4v*)(fp + 32);
        f4v f11 = *(const f4v*)(fp + 36);
        s8v fa0, fa1;
        #pragma unroll
        for (int j = 0; j < 4; ++j) {
            fa0[j] = f2bf(f00[j]); fa0[4 + j] = f2bf(f01[j]);
            fa1[j] = f2bf(f10[j]); fa1[4 + j] = f2bf(f11[j]);
        }
        #pragma unroll
        for (int t = 0; t < 2; ++t) {
            const int u16 = 2 * w + t;
            s8v kb0 = *(const s8v*)&kerF[(u16 * 2 + 0) * 512 + lane * 8];
            s8v kb1 = *(const s8v*)&kerF[(u16 * 2 + 1) * 512 + lane * 8];
            f4v wacc = {};
            wacc = __builtin_amdgcn_mfma_f32_16x16x32_bf16(fa0, kb0, wacc, 0, 0, 0);
            wacc = __builtin_amdgcn_mfma_f32_16x16x32_bf16(fa1, kb1, wacc, 0, 0, 0);
            // wacc[r] = W[n][u], n = 16*n16 + 4*qd + r, u = 16*u16 + c16.
            // B-frag slot: k32 = n16>>1, q = 2*(n16&1) + (qd>>1), j = 4*(qd&1)+r.
            s4v pv;
            #pragma unroll
            for (int r = 0; r < 4; ++r) pv[r] = f2bf(wacc[r]);
            *(s4v*)(wOut + (u16 * 4 + (n16 >> 1)) * 512
                         + ((2 * (n16 & 1) + (qd >> 1)) * 16 + c16) * 8
                         + 4 * (qd & 1)) = pv;
        }
    }
}

// ---------------------------------------------------------------------------
// Kernel B: out[b, 16-row octant] = relu(sum_e adj[b,e] @ W[b,e]).
// No LDS, no barriers. 4 waves split u (32 each). adj reg-direct; W-frag
// global loads coalesced (lane*16B). W[e] issued before adj[e+1] so the MFMA
// wait is a counted vmcnt, leaving the adjacency prefetch in flight.
// ---------------------------------------------------------------------------
__global__ __launch_bounds__(256, 4)
void out_kernel(const float* __restrict__ adj,
                const short* __restrict__ wsF,
                float* __restrict__ out)
{
    const int bid = blockIdx.x;
    const int wg  = ((bid & 7) << 8) | (bid >> 3);   // 2048 = 8*256: bijective XCD swizzle
    const int b   = wg >> 3;
    const int R0  = 16 * (wg & 7);                   // this block's 16 output rows
    const int tid  = threadIdx.x;
    const int w    = tid >> 6;                       // wave 0..3
    const int lane = tid & 63;
    const int c16  = lane & 15;
    const int qd   = lane >> 4;

    const float* adjB = adj + (size_t)b * (5 * 128 * 128);
    const short* wB   = wsF + (size_t)b * 5 * 16384;
    float*       outB = out + (size_t)b * (128 * 128);

    // adj[0] strip into regs
    f4v a0[4], a1[4];
    {
        const float* ap = adjB + (R0 + c16) * 128 + 8 * qd;
        #pragma unroll
        for (int k = 0; k < 4; ++k) {
            a0[k] = *(const f4v*)(ap + 32 * k);
            a1[k] = *(const f4v*)(ap + 32 * k + 4);
        }
    }

    f4v oacc[2] = {};  // u16 = 2w, 2w+1

    for (int e = 0; e < 5; ++e) {
        // convert adj[e] (vmcnt wait on loads issued one iteration ago)
        s8v af[4];
        #pragma unroll
        for (int k = 0; k < 4; ++k)
            #pragma unroll
            for (int j = 0; j < 4; ++j) {
                af[k][j]     = f2bf(a0[k][j]);
                af[k][4 + j] = f2bf(a1[k][j]);
            }

        // W[e] frag loads FIRST (so their wait below is vmcnt(8), not 0) ...
        s8v wv[8];
        #pragma unroll
        for (int t = 0; t < 2; ++t)
            #pragma unroll
            for (int k = 0; k < 4; ++k)
                wv[t * 4 + k] = *(const s8v*)&wB[e * 16384 + ((2 * w + t) * 4 + k) * 512 + lane * 8];

        // ... then issue adj[e+1]; it stays in flight through the MFMAs.
        if (e < 4) {
            const float* ap = adjB + (e + 1) * 16384 + (R0 + c16) * 128 + 8 * qd;
            #pragma unroll
            for (int k = 0; k < 4; ++k) {
                a0[k] = *(const f4v*)(ap + 32 * k);
                a1[k] = *(const f4v*)(ap + 32 * k + 4);
            }
            __builtin_amdgcn_sched_barrier(0);  // loads may not sink below this point
        }

        #pragma unroll
        for (int t = 0; t < 2; ++t)
            #pragma unroll
            for (int k = 0; k < 4; ++k)
                oacc[t] = __builtin_amdgcn_mfma_f32_16x16x32_bf16(af[k], wv[t * 4 + k], oacc[t], 0, 0, 0);
    }

    // relu + store
    #pragma unroll
    for (int t = 0; t < 2; ++t)
        #pragma unroll
        for (int r = 0; r < 4; ++r)
            outB[(R0 + 4 * qd + r) * 128 + 16 * (2 * w + t) + c16] = fmaxf(oacc[t][r], 0.f);
}

// ---------------------------------------------------------------------------
// Fallback: v6 single kernel (harness-verified), used if ws is too small.
// ---------------------------------------------------------------------------
__global__ __launch_bounds__(1024, 4)
void rgc_kernel(const float* __restrict__ adj,
                const float* __restrict__ feat,
                const float* __restrict__ ker,
                float* __restrict__ out)
{
    __shared__ __align__(16) short featA[16 * 512];
    __shared__ __align__(16) short kerB[5][16 * 512];
    __shared__ __align__(16) short WB[2][32 * 512];

    const int tid  = threadIdx.x;
    const int w    = tid >> 6;
    const int lane = tid & 63;
    const int c16  = lane & 15;
    const int quad = lane >> 4;
    const int g    = w >> 1;
    const int h    = w & 1;

    const int b = blockIdx.x;
    const float* adjB = adj  + (size_t)b * (5 * 128 * 128);
    const float* feG  = feat + (size_t)b * (128 * 64);
    const float* keG  = ker  + (size_t)b * (5 * 64 * 128);
    float*       outB = out  + (size_t)b * (128 * 128);

    f4v a0[4], a1[4];
    {
        const float* ap = adjB + (16 * g + c16) * 128 + 8 * quad;
        #pragma unroll
        for (int k16 = 0; k16 < 4; ++k16) {
            a0[k16] = *(const f4v*)(ap + 32 * k16);
            a1[k16] = *(const f4v*)(ap + 32 * k16 + 4);
        }
    }
    {
        const float* fp = feG + (16 * (w >> 1) + c16) * 64 + 32 * (w & 1) + 8 * quad;
        f4v f0 = *(const f4v*)(fp);
        f4v f1 = *(const f4v*)(fp + 4);
        s8v v;
        #pragma unroll
        for (int j = 0; j < 4; ++j) { v[j] = f2bf(f0[j]); v[4 + j] = f2bf(f1[j]); }
        *(s8v*)&featA[w * 512 + lane * 8] = v;
    }
    const int ku  = tid & 127;
    const int kd0 = (tid >> 7) * 8;
    const int kerB_off = (ku >> 4) * 1024 + (kd0 >> 5) * 512 + ((kd0 >> 3) & 3) * 128 + (ku & 15) * 8;
    {
        float kv[5][8];
        #pragma unroll
        for (int e = 0; e < 5; ++e)
            #pragma unroll
            for (int j = 0; j < 8; ++j)
                kv[e][j] = keG[e * (64 * 128) + (kd0 + j) * 128 + ku];
        #pragma unroll
        for (int e = 0; e < 5; ++e) {
            s8v v;
            #pragma unroll
            for (int j = 0; j < 8; ++j) v[j] = f2bf(kv[e][j]);
            *(s8v*)&kerB[e][kerB_off] = v;
        }
    }
    lds_barrier();

    const int wk16 = g >> 1;
    const int wqt  = 2 * (g & 1) + (quad >> 1);
    const int wj0  = 4 * (quad & 1);
    const int wbase = (wqt * 16 + c16) * 8 + wj0;

    {
        s8v fa0 = *(const s8v*)&featA[(g * 2 + 0) * 512 + lane * 8];
        s8v fa1 = *(const s8v*)&featA[(g * 2 + 1) * 512 + lane * 8];
        #pragma unroll
        for (int t = 0; t < 4; ++t) {
            const int u16 = 4 * h + t;
            s8v kb0 = *(const s8v*)&kerB[0][(u16 * 2 + 0) * 512 + lane * 8];
            s8v kb1 = *(const s8v*)&kerB[0][(u16 * 2 + 1) * 512 + lane * 8];
            f4v wacc = {};
            wacc = __builtin_amdgcn_mfma_f32_16x16x32_bf16(fa0, kb0, wacc, 0, 0, 0);
            wacc = __builtin_amdgcn_mfma_f32_16x16x32_bf16(fa1, kb1, wacc, 0, 0, 0);
            s4v pv;
            #pragma unroll
            for (int r = 0; r < 4; ++r) pv[r] = f2bf(wacc[r]);
            *(s4v*)&WB[0][(u16 * 4 + wk16) * 512 + wbase] = pv;
        }
    }
    lds_barrier();

    f4v oacc[4] = {};
    for (int e = 0; e < 5; ++e) {
        s8v af[4];
        #pragma unroll
        for (int k16 = 0; k16 < 4; ++k16) {
            #pragma unroll
            for (int j = 0; j < 4; ++j) {
                af[k16][j]     = f2bf(a0[k16][j]);
                af[k16][4 + j] = f2bf(a1[k16][j]);
            }
        }
        if (e < 4) {
            const float* ap = adjB + (e + 1) * (128 * 128) + (16 * g + c16) * 128 + 8 * quad;
            #pragma unroll
            for (int k16 = 0; k16 < 4; ++k16) {
                a0[k16] = *(const f4v*)(ap + 32 * k16);
                a1[k16] = *(const f4v*)(ap + 32 * k16 + 4);
            }
            __builtin_amdgcn_sched_barrier(0);

            s8v fa0 = *(const s8v*)&featA[(g * 2 + 0) * 512 + lane * 8];
            s8v fa1 = *(const s8v*)&featA[(g * 2 + 1) * 512 + lane * 8];
            #pragma unroll
            for (int t = 0; t < 4; ++t) {
                const int u16 = 4 * h + t;
                s8v kb0 = *(const s8v*)&kerB[e + 1][(u16 * 2 + 0) * 512 + lane * 8];
                s8v kb1 = *(const s8v*)&kerB[e + 1][(u16 * 2 + 1) * 512 + lane * 8];
                f4v wacc = {};
                wacc = __builtin_amdgcn_mfma_f32_16x16x32_bf16(fa0, kb0, wacc, 0, 0, 0);
                wacc = __builtin_amdgcn_mfma_f32_16x16x32_bf16(fa1, kb1, wacc, 0, 0, 0);
                s4v pv;
                #pragma unroll
                for (int r = 0; r < 4; ++r) pv[r] = f2bf(wacc[r]);
                *(s4v*)&WB[(e + 1) & 1][(u16 * 4 + wk16) * 512 + wbase] = pv;
            }
        }
        #pragma unroll
        for (int n = 0; n < 4; ++n) {
            const int u16 = 4 * h + n;
            #pragma unroll
            for (int k16 = 0; k16 < 4; ++k16) {
                s8v bfr = *(const s8v*)&WB[e & 1][(u16 * 4 + k16) * 512 + lane * 8];
                oacc[n] = __builtin_amdgcn_mfma_f32_16x16x32_bf16(af[k16], bfr, oacc[n], 0, 0, 0);
            }
        }
        if (e < 4) lds_barrier();
    }

    #pragma unroll
    for (int n = 0; n < 4; ++n)
        #pragma unroll
        for (int r = 0; r < 4; ++r)
            outB[(16 * g + 4 * quad + r) * 128 + 16 * (4 * h + n) + c16] = fmaxf(oacc[n][r], 0.f);
}

extern "C" void kernel_launch(void* const* d_in, const int* in_sizes, int n_in,
                              void* d_out, int out_size, void* d_ws, size_t ws_size,
                              hipStream_t stream)
{
    const float* adj  = (const float*)d_in[0];
    const float* feat = (const float*)d_in[1];
    const float* ker  = (const float*)d_in[2];
    const size_t W_BYTES = (size_t)1280 * 16384 * sizeof(short);  // 41.94 MB
    if (ws_size >= W_BYTES) {
        w_kernel<<<1280, 256, 0, stream>>>(feat, ker, (short*)d_ws);
        out_kernel<<<2048, 256, 0, stream>>>(adj, (const short*)d_ws, (float*)d_out);
    } else {
        rgc_kernel<<<256, 1024, 0, stream>>>(adj, feat, ker, (float*)d_out);
    }
}

// Round 9
// 168.775 us; speedup vs baseline: 1.2749x; 1.2749x over previous
//
#include <hip/hip_runtime.h>

// RelationalGraphConvLayer: out[b,m,u] = relu(sum_e (adj[b,e]@feat[b]) @ ker[b,e])
// B=256, E=5, N=128, ATOM=64, UNITS=128, fp32 in/out, bf16 MFMA compute.
//
// v8 (resubmit; prior round hit the same infra error Round 1 recovered from):
// counted-vmcnt DMA pipeline for the adjacency stream.
// Root cause identified in v0-v7: every version drained vmcnt to 0 each e
// (convert needs the whole reg batch) -> prefetch depth 1, ~2-8 KB in flight
// per CU -> ~10 GB/s/CU latency-bound floor (= the invariant ~60 us).
// Fix: adj staged via __builtin_amdgcn_global_load_lds (16 B/lane) into
// wave-private LDS tiles stored in A-frag order (per-lane GLOBAL address does
// the layout permutation; LDS dest stays linear -> conflict-free ds_read_b128
// at lane*16). 4-unit ring per wave, steady-state wait = s_waitcnt vmcnt(22)
// (never 0): ~8 KB DMA in flight per wave, ~64 KB per CU, continuously.
// Ker: v2-style reg-staged bf16 double-buffer, one lgkm-only barrier per e
// (global DMAs stay in flight across it). feat/YA layouts verbatim from
// verified v2/v5. LDS: adjF 64K + kerF 32K + featB 16K + YA 16K = 128 KB.

typedef __attribute__((ext_vector_type(8))) short s8v;  // 8 x bf16 MFMA A/B frag
typedef __attribute__((ext_vector_type(4))) float f4v;  // MFMA C/D frag / float4

__device__ __forceinline__ short f2bf(float f) {
    // fp32 -> bf16 round-to-nearest-even (inputs finite; no NaN handling needed)
    unsigned u = __builtin_bit_cast(unsigned, f);
    u += 0x7FFFu + ((u >> 16) & 1u);
    return (short)(u >> 16);
}

// LDS-only barrier: drain this wave's LDS ops, then rendezvous. Global (vmcnt)
// DMAs stay outstanding across it. sched_barrier fences reordering.
__device__ __forceinline__ void lds_barrier() {
    asm volatile("s_waitcnt lgkmcnt(0)" ::: "memory");
    __builtin_amdgcn_s_barrier();
    __builtin_amdgcn_sched_barrier(0);
}

// 16 B per lane, global -> LDS DMA. LDS dest is wave-uniform base + lane*16.
typedef __attribute__((address_space(1))) const void gas_void;
typedef __attribute__((address_space(3))) void las_void;
__device__ __forceinline__ void gl_lds16(const float* g, float* l) {
#if __has_builtin(__builtin_amdgcn_global_load_lds)
    __builtin_amdgcn_global_load_lds((gas_void*)g, (las_void*)l, 16, 0, 0);
#else
    // fallback keeps structure (reg round-trip); experiment void but correct
    const int lane = threadIdx.x & 63;
    *(f4v*)(l + 4 * lane) = *(const f4v*)(g);
#endif
}

__global__ __launch_bounds__(512, 2)
void rgc_kernel(const float* __restrict__ adj,
                const float* __restrict__ feat,
                const float* __restrict__ ker,
                float* __restrict__ out)
{
    // adjF[w][k16]: one 16-row x 32-col fp32 A-frag unit (2 KB) per ring slot.
    //   half h (j=4h..4h+3) at [h*256 + lane*4]: exactly the linear DMA layout.
    // kerF[buf] tile (u16*2+kk), lane l: ker[32kk+8q+j][16u16+(l&15)]  (B-frag)
    // featB tile (d16*4+k16),  lane l: feat[32k16+8q+j][16d16+(l&15)]  (B-frag)
    // YA[w] tile kk,           lane l: Y[16w+(l&15)][32kk+8q+j]        (A-frag)
    __shared__ __align__(16) float adjF[8][4][512];   // 64 KB
    __shared__ __align__(16) short kerF[2][16 * 512]; // 32 KB
    __shared__ __align__(16) short featB[16 * 512];   // 16 KB
    __shared__ __align__(16) short YA[8][1024];       // 16 KB

    const int tid  = threadIdx.x;
    const int w    = tid >> 6;    // wave 0..7: owns output rows [16w, 16w+16)
    const int lane = tid & 63;
    const int c16  = lane & 15;
    const int quad = lane >> 4;

    const int b = blockIdx.x;
    const float* adjB = adj  + (size_t)b * (5 * 128 * 128);
    const float* feG  = feat + (size_t)b * (128 * 64);
    const float* keG  = ker  + (size_t)b * (5 * 64 * 128);
    float*       outB = out  + (size_t)b * (128 * 128);

    // per-lane adj source base: row 16w+c16, col 8*quad (A-frag order)
    const float* aRow = adjB + (16 * w + c16) * 128 + 8 * quad;

    // ---- prologue: issue feat + ker[0] scalar loads, THEN adj e=0 DMAs ----
    const int fd = tid & 63;                 // feat: d (coalesced across lanes)
    float fv[16];
    #pragma unroll
    for (int i = 0; i < 2; ++i)
        #pragma unroll
        for (int j = 0; j < 8; ++j)
            fv[i * 8 + j] = feG[(i * 64 + (tid >> 6) * 8 + j) * 64 + fd];

    const int ku   = tid & 127;              // ker: u (coalesced across lanes)
    const int kd0a = (tid >> 7) * 8;
    const int kd0b = 32 + kd0a;
    const int kOffA = (ku >> 4) * 1024 + (kd0a >> 5) * 512 + ((kd0a >> 3) & 3) * 128 + (ku & 15) * 8;
    const int kOffB = (ku >> 4) * 1024 + (kd0b >> 5) * 512 + ((kd0b >> 3) & 3) * 128 + (ku & 15) * 8;
    float kva[8], kvb[8];
    #pragma unroll
    for (int j = 0; j < 8; ++j) { kva[j] = keG[(kd0a + j) * 128 + ku]; kvb[j] = keG[(kd0b + j) * 128 + ku]; }

    #pragma unroll
    for (int k16 = 0; k16 < 4; ++k16) {      // adj e=0 DMAs (stay in flight)
        gl_lds16(aRow + 32 * k16,     &adjF[w][k16][0]);
        gl_lds16(aRow + 32 * k16 + 4, &adjF[w][k16][256]);
    }
    __builtin_amdgcn_sched_barrier(0);

    // convert feat (compiler waits vmcnt(24): adj DMAs stay in flight)
    #pragma unroll
    for (int i = 0; i < 2; ++i) {
        const int fn0 = i * 64 + (tid >> 6) * 8;
        s8v v;
        #pragma unroll
        for (int j = 0; j < 8; ++j) v[j] = f2bf(fv[i * 8 + j]);
        *(s8v*)&featB[((fd >> 4) * 4 + (fn0 >> 5)) * 512 + ((fn0 >> 3) & 3) * 128 + (fd & 15) * 8] = v;
    }
    // convert ker[0] (compiler waits vmcnt(8))
    {
        s8v va, vb;
        #pragma unroll
        for (int j = 0; j < 8; ++j) { va[j] = f2bf(kva[j]); vb[j] = f2bf(kvb[j]); }
        *(s8v*)&kerF[0][kOffA] = va;
        *(s8v*)&kerF[0][kOffB] = vb;
    }
    lds_barrier();

    f4v oacc[8] = {};  // out tiles u16 = 0..7 for rows [16w, 16w+16)

    for (int e = 0; e < 5; ++e) {
        // ---- issue ker[e+1] scalar loads; pinned (v2 showed they sink) ----
        float nka[8], nkb[8];
        if (e < 4) {
            const float* kp = keG + (e + 1) * (64 * 128);
            #pragma unroll
            for (int j = 0; j < 8; ++j) { nka[j] = kp[(kd0a + j) * 128 + ku]; nkb[j] = kp[(kd0b + j) * 128 + ku]; }
            __builtin_amdgcn_sched_barrier(0);
        }

        // ---- matmul1 over 4 k16-units: consume (e,k16), reissue (e+1,k16) ----
        f4v yacc[4] = {};
        #pragma unroll
        for (int k16 = 0; k16 < 4; ++k16) {
            // steady state: younger ops = 6-2*k16 (this e's later units)
            // + 16 (ker[e+1]) + 2*k16 (already reissued units) = 22, constant.
            if (e < 4) asm volatile("s_waitcnt vmcnt(22)" ::: "memory");
            else       asm volatile("s_waitcnt vmcnt(0)"  ::: "memory");
            __builtin_amdgcn_sched_barrier(0);
            const f4v x0 = *(const f4v*)&adjF[w][k16][lane * 4];        // linear: conflict-free
            const f4v x1 = *(const f4v*)&adjF[w][k16][256 + lane * 4];
            asm volatile("s_waitcnt lgkmcnt(0)" ::: "memory");          // regs hold data before slot reuse
            __builtin_amdgcn_sched_barrier(0);
            if (e < 4) {                                                // reissue slot for e+1
                const float* src = aRow + (e + 1) * 16384 + 32 * k16;
                gl_lds16(src,     &adjF[w][k16][0]);
                gl_lds16(src + 4, &adjF[w][k16][256]);
            }
            __builtin_amdgcn_sched_barrier(0);
            s8v af;
            #pragma unroll
            for (int j = 0; j < 4; ++j) { af[j] = f2bf(x0[j]); af[4 + j] = f2bf(x1[j]); }
            #pragma unroll
            for (int d16 = 0; d16 < 4; ++d16) {
                s8v bf = *(const s8v*)&featB[(d16 * 4 + k16) * 512 + lane * 8];
                yacc[d16] = __builtin_amdgcn_mfma_f32_16x16x32_bf16(af, bf, yacc[d16], 0, 0, 0);
            }
        }

        // ---- Y -> wave-private LDS in A-frag order (v2 remap, verified) ----
        #pragma unroll
        for (int d16 = 0; d16 < 4; ++d16) {
            const int base = (d16 >> 1) * 512 + ((2 * d16 + (c16 >> 3)) & 3) * 128 + (c16 & 7);
            #pragma unroll
            for (int r = 0; r < 4; ++r)
                YA[w][base + (4 * quad + r) * 8] = f2bf(yacc[d16][r]);
        }

        // ---- matmul2: out[16 rows][all 128 u] += Y @ ker_e ----
        {
            s8v afr0 = *(const s8v*)&YA[w][lane * 8];
            s8v afr1 = *(const s8v*)&YA[w][512 + lane * 8];
            #pragma unroll
            for (int u16 = 0; u16 < 8; ++u16) {
                s8v b0 = *(const s8v*)&kerF[e & 1][(u16 * 2 + 0) * 512 + lane * 8];
                s8v b1 = *(const s8v*)&kerF[e & 1][(u16 * 2 + 1) * 512 + lane * 8];
                oacc[u16] = __builtin_amdgcn_mfma_f32_16x16x32_bf16(afr0, b0, oacc[u16], 0, 0, 0);
                oacc[u16] = __builtin_amdgcn_mfma_f32_16x16x32_bf16(afr1, b1, oacc[u16], 0, 0, 0);
            }
        }

        // ---- convert+store ker[e+1] (compiler waits vmcnt(8): the 8 reissued
        //      adj DMAs stay in flight), then lgkm-only barrier ----
        if (e < 4) {
            s8v va, vb;
            #pragma unroll
            for (int j = 0; j < 8; ++j) { va[j] = f2bf(nka[j]); vb[j] = f2bf(nkb[j]); }
            *(s8v*)&kerF[(e + 1) & 1][kOffA] = va;
            *(s8v*)&kerF[(e + 1) & 1][kOffB] = vb;
            lds_barrier();
        }
    }

    // ---- epilogue: relu + store ----
    #pragma unroll
    for (int u16 = 0; u16 < 8; ++u16)
        #pragma unroll
        for (int r = 0; r < 4; ++r)
            outB[(16 * w + 4 * quad + r) * 128 + 16 * u16 + c16] = fmaxf(oacc[u16][r], 0.f);
}

extern "C" void kernel_launch(void* const* d_in, const int* in_sizes, int n_in,
                              void* d_out, int out_size, void* d_ws, size_t ws_size,
                              hipStream_t stream)
{
    const float* adj  = (const float*)d_in[0];
    const float* feat = (const float*)d_in[1];
    const float* ker  = (const float*)d_in[2];
    rgc_kernel<<<256, 512, 0, stream>>>(adj, feat, ker, (float*)d_out);
}